// Round 5
// baseline (182.037 us; speedup 1.0000x reference)
//
#include <hip/hip_runtime.h>
#include <hip/hip_bf16.h>

#define N_NODES 100000
#define N_EDGES 800000
#define HIDDEN 128

typedef short frag_ab __attribute__((ext_vector_type(8)));   // 8 x bf16
typedef float frag_cd __attribute__((ext_vector_type(4)));   // 4 x f32

// round-to-nearest-even fp32 -> bf16 (scalar)
__device__ inline unsigned short f2b(float f) {
    union { float f; unsigned u; } x; x.f = f;
    return (unsigned short)((x.u + 0x7fffu + ((x.u >> 16) & 1u)) >> 16);
}

// packed pair fp32 -> bf16x2 (v_cvt_pk_bf16_f32 on gfx950)
__device__ inline unsigned pk2(float x, float y) {
    union { __hip_bfloat162 h; unsigned u; } c;
    c.h = __float22bfloat162_rn(make_float2(x, y));
    return c.u;
}

// ---------------------------------------------------------------------------
// Kernel 0: transpose+convert W1 (256x128 fp32) -> Bt[256][128] bf16, k-contig.
// ---------------------------------------------------------------------------
__global__ __launch_bounds__(256) void transpose_w1(
    const float* __restrict__ W1, unsigned short* __restrict__ Bt)
{
    const int t  = threadIdx.x;
    const int nc = blockIdx.x * 4 + (t >> 6);
    const int k2 = (t & 63) * 2;
    const int col  = nc & 127;
    const int roff = (nc >= 128) ? 128 : 0;
    float f0 = W1[(size_t)(roff + k2)     * HIDDEN + col];
    float f1 = W1[(size_t)(roff + k2 + 1) * HIDDEN + col];
    *(unsigned*)(Bt + (size_t)nc * HIDDEN + k2) = (unsigned)f2b(f0) | ((unsigned)f2b(f1) << 16);
}

// ---------------------------------------------------------------------------
// Kernel 1 (MFMA GEMM): UV = z @ [W1src|W1dst] + [b1|0] -> uint8, per-node
// row scales. R15: fully WAVE-AUTONOMOUS — zero LDS, zero barriers.
// R14 post-mortem: barrier-coupled staging kept precompute at ~48 us (floor
// ~13) despite 16 waves/CU; the stage->sync->MFMA->sync lockstep never
// amortized at ~3 tiles/block.
// Structure: one wave owns 16 nodes x all 256 features. Operand-swapped MFMA
// (A = W-frag from Bt GLOBAL — 64 KB, L1/L2-resident, each read is 16 full
// 64B lines; B = z-frag from global fp32, packed in-reg via v_cvt_pk) ->
// C[feature][node]: node = lc, feature = mt*16 + g*4 + r. acc = 16 frags
// (64 regs). Per-node absmax: in-lane fmax + 2 shfl across g. Bias folded by
// overwriting acc during the max pass. 100000 = 6250*16 -> no tail.
// No __launch_bounds__ forcing (R6/R12: forcing caps regs and spills).
// ---------------------------------------------------------------------------
__global__ __launch_bounds__(256) void precompute_uv_mfma(
    const float* __restrict__ z, const unsigned short* __restrict__ Bt,
    const float* __restrict__ b1, unsigned char* __restrict__ UVq,
    float* __restrict__ scales)
{
    const int t = threadIdx.x;
    const int lane = t & 63;
    const int w = t >> 6;
    const int g  = lane >> 4;
    const int lc = lane & 15;

    const int gid = blockIdx.x * 4 + w;          // wave-group id, 16 nodes each
    if (gid >= N_NODES / 16) return;
    const int node = gid * 16 + lc;

    // --- z fragments for this wave's 16 nodes: lane (g,lc) loads 32 B per q
    //     from z[node][q*32+g*8 .. +7], packs fp32->bf16 in-register. ---
    const float4* zrow = (const float4*)z + (size_t)node * 32;
    frag_ab zf[4];
    #pragma unroll
    for (int q = 0; q < 4; ++q) {
        float4 v0 = zrow[q * 8 + g * 2];
        float4 v1 = zrow[q * 8 + g * 2 + 1];
        union { unsigned u[4]; frag_ab f; } pk;
        pk.u[0] = pk2(v0.x, v0.y);
        pk.u[1] = pk2(v0.z, v0.w);
        pk.u[2] = pk2(v1.x, v1.y);
        pk.u[3] = pk2(v1.z, v1.w);
        zf[q] = pk.f;
    }

    // --- K loop: 64 MFMA, W-frags streamed from Bt (global, cache-hot) ---
    frag_cd acc[16];
    #pragma unroll
    for (int mt = 0; mt < 16; ++mt)
        acc[mt] = (frag_cd){0.f, 0.f, 0.f, 0.f};
    #pragma unroll
    for (int q = 0; q < 4; ++q) {
        #pragma unroll
        for (int mt = 0; mt < 16; ++mt) {
            frag_ab wf = *(const frag_ab*)(Bt + (size_t)(mt * 16 + lc) * HIDDEN
                                              + q * 32 + g * 8);
            acc[mt] = __builtin_amdgcn_mfma_f32_16x16x32_bf16(wf, zf[q], acc[mt], 0, 0, 0);
        }
    }
    // C layout: feature = mt*16 + g*4 + r, node col = lc (verified R14)

    // --- bias fold (U half only) + per-node per-half absmax ---
    const float4* b1f4 = (const float4*)b1;
    float mxU = 0.f, mxV = 0.f;
    #pragma unroll
    for (int mt = 0; mt < 8; ++mt) {            // U half: += b1, track max
        float4 bb = b1f4[mt * 4 + g];
        acc[mt][0] += bb.x; acc[mt][1] += bb.y;
        acc[mt][2] += bb.z; acc[mt][3] += bb.w;
        #pragma unroll
        for (int r = 0; r < 4; ++r)
            mxU = fmaxf(mxU, fabsf(acc[mt][r]));
    }
    #pragma unroll
    for (int mt = 8; mt < 16; ++mt)             // V half: no bias
        #pragma unroll
        for (int r = 0; r < 4; ++r)
            mxV = fmaxf(mxV, fabsf(acc[mt][r]));

    mxU = fmaxf(mxU, __shfl_xor(mxU, 16));
    mxU = fmaxf(mxU, __shfl_xor(mxU, 32));
    mxV = fmaxf(mxV, __shfl_xor(mxV, 16));
    mxV = fmaxf(mxV, __shfl_xor(mxV, 32));
    mxU = fmaxf(mxU, 1e-12f);
    mxV = fmaxf(mxV, 1e-12f);
    const float ainvU = 127.0f / mxU;
    const float ainvV = 127.0f / mxV;

    // --- quantize + store: per mt one packed dword at UVq[node*256+mt*16+g*4] ---
    unsigned char* urow = UVq + (size_t)node * 256;
    #pragma unroll
    for (int mt = 0; mt < 16; ++mt) {
        const float ainv = (mt < 8) ? ainvU : ainvV;
        unsigned q0 = (unsigned)__builtin_fmaf(acc[mt][0], ainv, 128.5f);
        unsigned q1 = (unsigned)__builtin_fmaf(acc[mt][1], ainv, 128.5f);
        unsigned q2 = (unsigned)__builtin_fmaf(acc[mt][2], ainv, 128.5f);
        unsigned q3 = (unsigned)__builtin_fmaf(acc[mt][3], ainv, 128.5f);
        *(unsigned*)&urow[mt * 16 + g * 4] = q0 | (q1 << 8) | (q2 << 16) | (q3 << 24);
    }
    if (g == 0) {
        scales[node * 2 + 0] = mxU * (1.0f / 127.0f);
        scales[node * 2 + 1] = mxV * (1.0f / 127.0f);
    }
}

// ---------------------------------------------------------------------------
// Kernel 2: per-edge score = relu(aU*(u-128) + aV*(v-128)) . W2 + b2
// UNCHANGED (measured structure-invariant at the gather ceiling).
// ---------------------------------------------------------------------------
__device__ inline float dq4(unsigned uq, unsigned vq, float aU, float aV,
                            float k, float4 w, float acc) {
    #pragma unroll
    for (int b = 0; b < 4; ++b) {
        float uf = (float)((uq >> (8 * b)) & 0xffu);
        float vf = (float)((vq >> (8 * b)) & 0xffu);
        float h  = __builtin_fmaf(aU, uf, __builtin_fmaf(aV, vf, k));
        h = fmaxf(h, 0.f);
        float wv = (b == 0) ? w.x : (b == 1) ? w.y : (b == 2) ? w.z : w.w;
        acc = __builtin_fmaf(h, wv, acc);
    }
    return acc;
}

__global__ __launch_bounds__(256) void edge_score(
    const int* __restrict__ ei, const unsigned char* __restrict__ UVq,
    const float* __restrict__ scales, const float* __restrict__ W2,
    const float* __restrict__ B2, float* __restrict__ out)
{
    const int t = threadIdx.x;
    const int g = t & 7;
    const int slot = t >> 3;
    const int e0 = blockIdx.x * 64 + slot;
    const int e1 = e0 + 32;

    const float4* W24 = (const float4*)W2;
    const float4 w0 = W24[g * 4 + 0];
    const float4 w1 = W24[g * 4 + 1];
    const float4 w2 = W24[g * 4 + 2];
    const float4 w3 = W24[g * 4 + 3];

    const int s0 = ei[e0];
    const int d0 = ei[N_EDGES + e0];
    const int s1 = ei[e1];
    const int d1 = ei[N_EDGES + e1];

    // 16 B/lane x 8 lanes = one 128 B row-half per edge side (1 dwordx4 each)
    const uint4 u0 = *(const uint4*)(UVq + (size_t)s0 * 256 + g * 16);
    const uint4 v0 = *(const uint4*)(UVq + (size_t)d0 * 256 + 128 + g * 16);
    const uint4 u1 = *(const uint4*)(UVq + (size_t)s1 * 256 + g * 16);
    const uint4 v1 = *(const uint4*)(UVq + (size_t)d1 * 256 + 128 + g * 16);
    const float aU0 = scales[s0 * 2];
    const float aV0 = scales[d0 * 2 + 1];
    const float aU1 = scales[s1 * 2];
    const float aV1 = scales[d1 * 2 + 1];

    const float k0 = -128.f * (aU0 + aV0);
    const float k1 = -128.f * (aU1 + aV1);

    float A = 0.f, B = 0.f;
    A = dq4(u0.x, v0.x, aU0, aV0, k0, w0, A);
    A = dq4(u0.y, v0.y, aU0, aV0, k0, w1, A);
    A = dq4(u0.z, v0.z, aU0, aV0, k0, w2, A);
    A = dq4(u0.w, v0.w, aU0, aV0, k0, w3, A);

    B = dq4(u1.x, v1.x, aU1, aV1, k1, w0, B);
    B = dq4(u1.y, v1.y, aU1, aV1, k1, w1, B);
    B = dq4(u1.z, v1.z, aU1, aV1, k1, w2, B);
    B = dq4(u1.w, v1.w, aU1, aV1, k1, w3, B);

    float sa = A;
    float sb = B;
    sa += __shfl_xor(sa, 1, 8);
    sa += __shfl_xor(sa, 2, 8);
    sa += __shfl_xor(sa, 4, 8);
    sb += __shfl_xor(sb, 1, 8);
    sb += __shfl_xor(sb, 2, 8);
    sb += __shfl_xor(sb, 4, 8);

    if (g == 0) {
        float bb = B2[0];
        out[e0] = sa + bb;
        out[e1] = sb + bb;
    }
}

extern "C" void kernel_launch(void* const* d_in, const int* in_sizes, int n_in,
                              void* d_out, int out_size, void* d_ws, size_t ws_size,
                              hipStream_t stream) {
    const float* z  = (const float*)d_in[0];
    const int*   ei = (const int*)d_in[1];
    const float* W1 = (const float*)d_in[2];
    const float* b1 = (const float*)d_in[3];
    const float* W2 = (const float*)d_in[4];
    const float* b2 = (const float*)d_in[5];
    float* out = (float*)d_out;

    unsigned char* UVq = (unsigned char*)d_ws;                       // 25.6 MB
    float* scales = (float*)(UVq + (size_t)N_NODES * 256);           // 800 KB (U,V scale pairs)
    unsigned short* Bt = (unsigned short*)(scales + 2 * N_NODES);    // 64 KB, 16B-aligned

    transpose_w1<<<64, 256, 0, stream>>>(W1, Bt);
    precompute_uv_mfma<<<(N_NODES / 16 + 3) / 4, 256, 0, stream>>>(z, Bt, b1, UVq, scales);
    edge_score<<<N_EDGES / 64, 256, 0, stream>>>(ei, UVq, scales, W2, b2, out);
}

// Round 6
// 142.690 us; speedup vs baseline: 1.2758x; 1.2758x over previous
//
#include <hip/hip_runtime.h>
#include <hip/hip_bf16.h>

#define N_NODES 100000
#define N_EDGES 800000
#define HIDDEN 128
#define NGROUPS 6250            // 100000 / 16 nodes per wave-group
#define PC_BLOCKS 512           // 2 blocks/CU (64 KB LDS each), 4 waves/block
#define PC_STRIDE 2048          // PC_BLOCKS * 4 waves

typedef short frag_ab __attribute__((ext_vector_type(8)));   // 8 x bf16
typedef float frag_cd __attribute__((ext_vector_type(4)));   // 4 x f32

// round-to-nearest-even fp32 -> bf16 (scalar)
__device__ inline unsigned short f2b(float f) {
    union { float f; unsigned u; } x; x.f = f;
    return (unsigned short)((x.u + 0x7fffu + ((x.u >> 16) & 1u)) >> 16);
}

// packed pair fp32 -> bf16x2 (v_cvt_pk_bf16_f32 on gfx950)
__device__ inline unsigned pk2(float x, float y) {
    union { __hip_bfloat162 h; unsigned u; } c;
    c.h = __float22bfloat162_rn(make_float2(x, y));
    return c.u;
}

// ---------------------------------------------------------------------------
// Kernel 0: transpose+convert W1 (256x128 fp32) -> Bt[256][128] bf16, k-contig.
// ---------------------------------------------------------------------------
__global__ __launch_bounds__(256) void transpose_w1(
    const float* __restrict__ W1, unsigned short* __restrict__ Bt)
{
    const int t  = threadIdx.x;
    const int nc = blockIdx.x * 4 + (t >> 6);
    const int k2 = (t & 63) * 2;
    const int col  = nc & 127;
    const int roff = (nc >= 128) ? 128 : 0;
    float f0 = W1[(size_t)(roff + k2)     * HIDDEN + col];
    float f1 = W1[(size_t)(roff + k2 + 1) * HIDDEN + col];
    *(unsigned*)(Bt + (size_t)nc * HIDDEN + k2) = (unsigned)f2b(f0) | ((unsigned)f2b(f1) << 16);
}

// ---------------------------------------------------------------------------
// Kernel 1 (MFMA GEMM): UV = z @ [W1src|W1dst] + [b1|0] -> uint8 + row scales.
// R16: R15's wave-autonomous structure KEPT (one wave owns 16 nodes x 256
// features, C[feature][node], in-lane absmax, no inter-wave coupling), but
// W fragments now come from LDS instead of global. R15 post-mortem: global
// W-frag loads put ~200cyc L2 latency in series with every MFMA (compiler
// emits load->wait->MFMA 1:1) -> 74 us, MfmaUtil 3%. W is 64 KB: stage it
// ONCE per block (single barrier in the whole kernel), chunk-major layout
// lds_frag[s*256+row] (s = k-chunk q*4+g, row = feature) so the wave's
// ds_read_b128 at (mt,q) is 16 contiguous frags across lc -> minimum bank
// phases. z stays register-direct; next group's z is issued BEFORE the
// K-loop (issue-early/consume-late) and consumed after, hiding HBM latency
// under 64 MFMAs + epilogue. Persistent: 512 blocks x 4 waves, ~3 groups
// per wave. No __launch_bounds__ forcing (R6/R12: forcing -> spill).
// ---------------------------------------------------------------------------
__global__ __launch_bounds__(256) void precompute_uv_mfma(
    const float* __restrict__ z, const unsigned short* __restrict__ Bt,
    const float* __restrict__ b1, unsigned char* __restrict__ UVq,
    float* __restrict__ scales)
{
    __shared__ unsigned short smem[4096 * 8];        // 64 KB: Bt chunk-major [s][row]
    const int t = threadIdx.x;
    const int lane = t & 63;
    const int w = t >> 6;
    const int g  = lane >> 4;
    const int lc = lane & 15;

    // --- one-time stage: Bt (64 KB) -> LDS. Thread t copies row t's 16
    //     chunks; dst frag = s*256 + row -> contiguous 1 KB LDS writes. ---
    {
        const uint4* bt4 = (const uint4*)Bt;
        uint4* s4 = (uint4*)smem;
        #pragma unroll
        for (int k = 0; k < 16; ++k)
            s4[k * 256 + t] = bt4[t * 16 + k];       // row = t, s = k
    }
    __syncthreads();                                  // the only barrier

    const float4* zbase = (const float4*)z;
    const float4* b1f4  = (const float4*)b1;
    const frag_ab* wlds = (const frag_ab*)smem;

    int gid = blockIdx.x * 4 + w;                     // < 2048 <= NGROUPS
    float4 cur[8];
    {   // prologue z load: lane (g,lc) reads z[gid*16+lc][q*32+g*8 .. +7]
        const float4* zrow = zbase + (size_t)(gid * 16 + lc) * 32;
        #pragma unroll
        for (int i = 0; i < 8; ++i)
            cur[i] = zrow[(i >> 1) * 8 + g * 2 + (i & 1)];
    }

    while (true) {
        // --- pack current z -> bf16 fragments ---
        frag_ab zf[4];
        #pragma unroll
        for (int q = 0; q < 4; ++q) {
            union { unsigned u[4]; frag_ab f; } pk;
            pk.u[0] = pk2(cur[q * 2].x,     cur[q * 2].y);
            pk.u[1] = pk2(cur[q * 2].z,     cur[q * 2].w);
            pk.u[2] = pk2(cur[q * 2 + 1].x, cur[q * 2 + 1].y);
            pk.u[3] = pk2(cur[q * 2 + 1].z, cur[q * 2 + 1].w);
            zf[q] = pk.f;
        }

        // --- issue next group's z loads (consumed after the K-loop) ---
        const int nxt = gid + PC_STRIDE;
        const bool have = (nxt < NGROUPS);
        if (have) {
            const float4* zrow = zbase + (size_t)(nxt * 16 + lc) * 32;
            #pragma unroll
            for (int i = 0; i < 8; ++i)
                cur[i] = zrow[(i >> 1) * 8 + g * 2 + (i & 1)];
        }

        // --- K loop: 64 ds_read_b128 + 64 MFMA (A = W from LDS, B = zf) ---
        frag_cd acc[16];
        #pragma unroll
        for (int mt = 0; mt < 16; ++mt)
            acc[mt] = (frag_cd){0.f, 0.f, 0.f, 0.f};
        #pragma unroll
        for (int q = 0; q < 4; ++q) {
            #pragma unroll
            for (int mt = 0; mt < 16; ++mt) {
                frag_ab wf = wlds[(q * 4 + g) * 256 + mt * 16 + lc];
                acc[mt] = __builtin_amdgcn_mfma_f32_16x16x32_bf16(wf, zf[q], acc[mt], 0, 0, 0);
            }
        }
        // C layout: feature = mt*16 + g*4 + r, node col = lc

        // --- bias fold (U half) + per-node per-half absmax ---
        float mxU = 0.f, mxV = 0.f;
        #pragma unroll
        for (int mt = 0; mt < 8; ++mt) {
            float4 bb = b1f4[mt * 4 + g];
            acc[mt][0] += bb.x; acc[mt][1] += bb.y;
            acc[mt][2] += bb.z; acc[mt][3] += bb.w;
            #pragma unroll
            for (int r = 0; r < 4; ++r)
                mxU = fmaxf(mxU, fabsf(acc[mt][r]));
        }
        #pragma unroll
        for (int mt = 8; mt < 16; ++mt)
            #pragma unroll
            for (int r = 0; r < 4; ++r)
                mxV = fmaxf(mxV, fabsf(acc[mt][r]));

        mxU = fmaxf(mxU, __shfl_xor(mxU, 16));
        mxU = fmaxf(mxU, __shfl_xor(mxU, 32));
        mxV = fmaxf(mxV, __shfl_xor(mxV, 16));
        mxV = fmaxf(mxV, __shfl_xor(mxV, 32));
        mxU = fmaxf(mxU, 1e-12f);
        mxV = fmaxf(mxV, 1e-12f);
        const float ainvU = 127.0f / mxU;
        const float ainvV = 127.0f / mxV;

        // --- quantize + store ---
        const int node = gid * 16 + lc;
        unsigned char* urow = UVq + (size_t)node * 256;
        #pragma unroll
        for (int mt = 0; mt < 16; ++mt) {
            const float ainv = (mt < 8) ? ainvU : ainvV;
            unsigned q0 = (unsigned)__builtin_fmaf(acc[mt][0], ainv, 128.5f);
            unsigned q1 = (unsigned)__builtin_fmaf(acc[mt][1], ainv, 128.5f);
            unsigned q2 = (unsigned)__builtin_fmaf(acc[mt][2], ainv, 128.5f);
            unsigned q3 = (unsigned)__builtin_fmaf(acc[mt][3], ainv, 128.5f);
            *(unsigned*)&urow[mt * 16 + g * 4] = q0 | (q1 << 8) | (q2 << 16) | (q3 << 24);
        }
        if (g == 0) {
            scales[node * 2 + 0] = mxU * (1.0f / 127.0f);
            scales[node * 2 + 1] = mxV * (1.0f / 127.0f);
        }

        if (!have) break;
        gid = nxt;
    }
}

// ---------------------------------------------------------------------------
// Kernel 2: per-edge score = relu(aU*(u-128) + aV*(v-128)) . W2 + b2
// UNCHANGED (measured structure-invariant at the gather ceiling).
// ---------------------------------------------------------------------------
__device__ inline float dq4(unsigned uq, unsigned vq, float aU, float aV,
                            float k, float4 w, float acc) {
    #pragma unroll
    for (int b = 0; b < 4; ++b) {
        float uf = (float)((uq >> (8 * b)) & 0xffu);
        float vf = (float)((vq >> (8 * b)) & 0xffu);
        float h  = __builtin_fmaf(aU, uf, __builtin_fmaf(aV, vf, k));
        h = fmaxf(h, 0.f);
        float wv = (b == 0) ? w.x : (b == 1) ? w.y : (b == 2) ? w.z : w.w;
        acc = __builtin_fmaf(h, wv, acc);
    }
    return acc;
}

__global__ __launch_bounds__(256) void edge_score(
    const int* __restrict__ ei, const unsigned char* __restrict__ UVq,
    const float* __restrict__ scales, const float* __restrict__ W2,
    const float* __restrict__ B2, float* __restrict__ out)
{
    const int t = threadIdx.x;
    const int g = t & 7;
    const int slot = t >> 3;
    const int e0 = blockIdx.x * 64 + slot;
    const int e1 = e0 + 32;

    const float4* W24 = (const float4*)W2;
    const float4 w0 = W24[g * 4 + 0];
    const float4 w1 = W24[g * 4 + 1];
    const float4 w2 = W24[g * 4 + 2];
    const float4 w3 = W24[g * 4 + 3];

    const int s0 = ei[e0];
    const int d0 = ei[N_EDGES + e0];
    const int s1 = ei[e1];
    const int d1 = ei[N_EDGES + e1];

    // 16 B/lane x 8 lanes = one 128 B row-half per edge side (1 dwordx4 each)
    const uint4 u0 = *(const uint4*)(UVq + (size_t)s0 * 256 + g * 16);
    const uint4 v0 = *(const uint4*)(UVq + (size_t)d0 * 256 + 128 + g * 16);
    const uint4 u1 = *(const uint4*)(UVq + (size_t)s1 * 256 + g * 16);
    const uint4 v1 = *(const uint4*)(UVq + (size_t)d1 * 256 + 128 + g * 16);
    const float aU0 = scales[s0 * 2];
    const float aV0 = scales[d0 * 2 + 1];
    const float aU1 = scales[s1 * 2];
    const float aV1 = scales[d1 * 2 + 1];

    const float k0 = -128.f * (aU0 + aV0);
    const float k1 = -128.f * (aU1 + aV1);

    float A = 0.f, B = 0.f;
    A = dq4(u0.x, v0.x, aU0, aV0, k0, w0, A);
    A = dq4(u0.y, v0.y, aU0, aV0, k0, w1, A);
    A = dq4(u0.z, v0.z, aU0, aV0, k0, w2, A);
    A = dq4(u0.w, v0.w, aU0, aV0, k0, w3, A);

    B = dq4(u1.x, v1.x, aU1, aV1, k1, w0, B);
    B = dq4(u1.y, v1.y, aU1, aV1, k1, w1, B);
    B = dq4(u1.z, v1.z, aU1, aV1, k1, w2, B);
    B = dq4(u1.w, v1.w, aU1, aV1, k1, w3, B);

    float sa = A;
    float sb = B;
    sa += __shfl_xor(sa, 1, 8);
    sa += __shfl_xor(sa, 2, 8);
    sa += __shfl_xor(sa, 4, 8);
    sb += __shfl_xor(sb, 1, 8);
    sb += __shfl_xor(sb, 2, 8);
    sb += __shfl_xor(sb, 4, 8);

    if (g == 0) {
        float bb = B2[0];
        out[e0] = sa + bb;
        out[e1] = sb + bb;
    }
}

extern "C" void kernel_launch(void* const* d_in, const int* in_sizes, int n_in,
                              void* d_out, int out_size, void* d_ws, size_t ws_size,
                              hipStream_t stream) {
    const float* z  = (const float*)d_in[0];
    const int*   ei = (const int*)d_in[1];
    const float* W1 = (const float*)d_in[2];
    const float* b1 = (const float*)d_in[3];
    const float* W2 = (const float*)d_in[4];
    const float* b2 = (const float*)d_in[5];
    float* out = (float*)d_out;

    unsigned char* UVq = (unsigned char*)d_ws;                       // 25.6 MB
    float* scales = (float*)(UVq + (size_t)N_NODES * 256);           // 800 KB (U,V scale pairs)
    unsigned short* Bt = (unsigned short*)(scales + 2 * N_NODES);    // 64 KB, 16B-aligned

    transpose_w1<<<64, 256, 0, stream>>>(W1, Bt);
    precompute_uv_mfma<<<PC_BLOCKS, 256, 0, stream>>>(z, Bt, b1, UVq, scales);
    edge_score<<<N_EDGES / 64, 256, 0, stream>>>(ei, UVq, scales, W2, b2, out);
}